// Round 3
// baseline (226.151 us; speedup 1.0000x reference)
//
#include <hip/hip_runtime.h>
#include <math.h>

// MoE router: logits = x[16384,2048] @ W^T[2048,64]; softmax; top-2; renorm.
//
// R7/R8/R9 post-mortem: three different pipeline schedules (simple dbuf,
// depth-2 reg prefetch, counted-vmcnt raw barriers) ALL give router ~50us.
// Bottleneck is invariant across them: the barrier-synced LDS staging
// structure (per CU-step: ~1340cyc LDS port + ~1600cyc HBM, serialized).
//
// R10: NO LDS, NO K-loop barriers. Key fact (verified by the passing R7-R9
// kernels): mfma_f32_16x16x32_f16 A/B frag layout is lane(c=L&15,q=L>>4) ->
// row c, k-elems 8q..8q+8 -- row-contiguous. So:
//  - A-frags load DIRECTLY from global x (lanes c,c+16,c+32,c+48 cover 128B
//    contiguous per row), split to fp16 hi/lo in registers.
//  - B-frags load DIRECTLY from a fragment-ordered pre-split W image
//    (w_split2): 16B/lane perfectly coalesced, L2-resident (512KB).
//    x4 read amplification (no cross-wave sharing) = 512MB L2 = ~15us,
//    hidden under the 21us x HBM stream.
// Each wave owns 16 tokens x 64 experts x K-half(1024), free-running with
// register double-buffering (x and W one step ahead); no sched pins -- the
// compiler schedules. 2048 waves = 8/CU = 2/SIMD for TLP. One barrier pair
// remains: the kh-pair fp32 reduction through the small lg slab.
//
// fp16 split-precision MFMA (verified R5-R9, absmax 0.002): x=xh+xl, W=wh+wl,
// logits = xh*wh + xl*wh + xh*wl, fp32 acc.
//
// img granule g = ((((kk*16+s)*2+ch)*4+nt)*2+h)*64 + L : lane L holds hi/lo
// fp16 of W[nt*16+c][kk*1024 + s*64 + ch*32 + 8q .. +8].

typedef _Float16 half8  __attribute__((ext_vector_type(8)));
typedef float    floatx4 __attribute__((ext_vector_type(4)));

#define NTOK  16384
#define DDIM  2048
#define NE    64

__device__ inline void split8(const float4& a, const float4& b,
                              half8& hi, half8& lo) {
    float f[8] = {a.x, a.y, a.z, a.w, b.x, b.y, b.z, b.w};
#pragma unroll
    for (int j = 0; j < 8; ++j) {
        const _Float16 h = (_Float16)f[j];
        hi[j] = h;
        lo[j] = (_Float16)(f[j] - (float)h);
    }
}

// ---- kernel 1: pre-split W into fragment-ordered image (512 KB) ----
__global__ __launch_bounds__(256) void w_split2(const float* __restrict__ W,
                                                _Float16* __restrict__ img) {
    const int g  = blockIdx.x * 256 + threadIdx.x;  // granule idx 0..32767
    const int L  = g & 63;
    const int Bk = g >> 6;
    const int h  = Bk & 1;
    const int nt = (Bk >> 1) & 3;
    const int ch = (Bk >> 3) & 1;
    const int s  = (Bk >> 4) & 15;
    const int kk = (Bk >> 8) & 1;
    const int c  = L & 15, q = L >> 4;
    const float* src = W + (size_t)(nt * 16 + c) * DDIM
                         + kk * 1024 + s * 64 + ch * 32 + q * 8;
    const float4 a = *(const float4*)(src);
    const float4 b = *(const float4*)(src + 4);
    half8 hi, lo;
    split8(a, b, hi, lo);
    *(half8*)(img + (size_t)g * 8) = h ? lo : hi;
}

// ---- kernel 2: barrier-free per-wave MFMA GEMM + softmax + top-2 ----
__global__ __launch_bounds__(256, 2) void router_mfma(
    const float* __restrict__ x,
    const _Float16* __restrict__ img,
    float* __restrict__ out)
{
    __shared__ __align__(16) float lg[32 * 68];   // 8.5 KB logits slab

    const int tid = threadIdx.x;
    const int L   = tid & 63;
    const int wv  = __builtin_amdgcn_readfirstlane(tid >> 6);  // 0..3
    const int kk  = wv & 1;          // K half (0: k<1024, 1: k>=1024)
    const int tg  = wv >> 1;         // token group (16 tokens each)
    const int c   = L & 15, q = L >> 4;
    const int btok = blockIdx.x * 32;
    const int tok0 = btok + tg * 16;

    // per-lane bases: A row = token tok0+c, k base = kk*1024 + 8q
    const float*    xp = x + (size_t)(tok0 + c) * DDIM + kk * 1024 + q * 8;
    const _Float16* wp = img + (size_t)kk * 131072 + (size_t)L * 8;

    floatx4 acc[4];
#pragma unroll
    for (int nt = 0; nt < 4; ++nt) acc[nt] = (floatx4)0.f;

    float4 xb0[4], xb1[4];     // [2*ch + lohalf] : 8 floats per k32 chunk
    half8  wb0[16], wb1[16];   // [ch*8 + nt*2 + h]

    auto LX = [&](int s, float4* xb) {
#pragma unroll
        for (int ch = 0; ch < 2; ++ch) {
            xb[2 * ch + 0] = *(const float4*)(xp + s * 64 + ch * 32);
            xb[2 * ch + 1] = *(const float4*)(xp + s * 64 + ch * 32 + 4);
        }
    };
    auto LW = [&](int s, half8* wb) {
#pragma unroll
        for (int f = 0; f < 16; ++f)          // f = ch*8 + nt*2 + h
            wb[f] = *(const half8*)(wp + (size_t)s * 8192 + f * 512);
    };
    auto CP = [&](const float4* xb, const half8* wb) {
#pragma unroll
        for (int ch = 0; ch < 2; ++ch) {
            half8 Ah, Al;
            split8(xb[2 * ch], xb[2 * ch + 1], Ah, Al);
#pragma unroll
            for (int nt = 0; nt < 4; ++nt) {
                const half8 Bh = wb[ch * 8 + nt * 2];
                const half8 Bl = wb[ch * 8 + nt * 2 + 1];
                acc[nt] = __builtin_amdgcn_mfma_f32_16x16x32_f16(Ah, Bh, acc[nt], 0, 0, 0);
                acc[nt] = __builtin_amdgcn_mfma_f32_16x16x32_f16(Al, Bh, acc[nt], 0, 0, 0);
                acc[nt] = __builtin_amdgcn_mfma_f32_16x16x32_f16(Ah, Bl, acc[nt], 0, 0, 0);
            }
        }
    };

    // ---- free-running K loop: 16 steps of k64, reg double-buffered ----
    LX(0, xb0); LW(0, wb0);
#pragma unroll
    for (int b = 0; b < 16; b += 2) {
        LX(b + 1, xb1); LW(b + 1, wb1);      // issue next-step loads
        CP(xb0, wb0);
        if (b + 2 < 16) { LX(b + 2, xb0); LW(b + 2, wb0); }
        CP(xb1, wb1);
    }

    // ---- kh-pair reduction through lg (C/D: col=lane&15, row=(L>>4)*4+r) ----
    if (kk == 1) {
#pragma unroll
        for (int nt = 0; nt < 4; ++nt)
#pragma unroll
            for (int r = 0; r < 4; ++r)
                lg[(tg * 16 + q * 4 + r) * 68 + nt * 16 + c] = acc[nt][r];
    }
    __syncthreads();
    if (kk == 0) {
#pragma unroll
        for (int nt = 0; nt < 4; ++nt)
#pragma unroll
            for (int r = 0; r < 4; ++r) {
                const int o = (tg * 16 + q * 4 + r) * 68 + nt * 16 + c;
                lg[o] += acc[nt][r];
            }
    }
    __syncthreads();

    // ---- softmax + top-2: thread t < 32 owns token btok+t ----
    if (tid < 32) {
        const int token = btok + tid;
        float* row = &lg[tid * 68];
        float pr[NE];
#pragma unroll
        for (int e = 0; e < NE; ++e) pr[e] = row[e];

        float m = pr[0];
#pragma unroll
        for (int e = 1; e < NE; ++e) m = fmaxf(m, pr[e]);
        float s = 0.f;
#pragma unroll
        for (int e = 0; e < NE; ++e) { pr[e] = expf(pr[e] - m); s += pr[e]; }
        const float inv = 1.f / s;

        // lax.top_k tie-break = lowest index first -> strict '>' ascending scan
        float v1 = -1.f; int i1 = 0;
#pragma unroll
        for (int e = 0; e < NE; ++e) { if (pr[e] > v1) { v1 = pr[e]; i1 = e; } }
        float v2 = -1.f; int i2 = 0;
#pragma unroll
        for (int e = 0; e < NE; ++e) { if (e != i1 && pr[e] > v2) { v2 = pr[e]; i2 = e; } }

        const float ts = v1 + v2;
        float* out_tp = out;              // top_k_probs  [NTOK][2]
        float* out_ti = out + 2 * NTOK;   // top_k_indices[NTOK][2] (float values)
        *(float2*)(out_tp + token * 2) = make_float2(v1 / ts, v2 / ts);
        *(float2*)(out_ti + token * 2) = make_float2((float)i1, (float)i2);

#pragma unroll
        for (int e = 0; e < NE; ++e) row[e] = pr[e] * inv;
    }
    __syncthreads();

    // ---- cooperative coalesced probs write: 32 tok x 64 = 2048 floats ----
    {
        float* out_p = out + 4 * NTOK + (size_t)btok * NE;
#pragma unroll
        for (int i = 0; i < 2; ++i) {
            const int f = tid + 256 * i;        // float4 idx, 512 total
            const int r = f >> 4, c4 = f & 15;
            const float4 v = *(const float4*)&lg[r * 68 + 4 * c4];
            *(float4*)(out_p + f * 4) = v;
        }
    }
}

extern "C" void kernel_launch(void* const* d_in, const int* in_sizes, int n_in,
                              void* d_out, int out_size, void* d_ws, size_t ws_size,
                              hipStream_t stream) {
    const float* x = (const float*)d_in[0];
    const float* W = (const float*)d_in[1];
    float* out     = (float*)d_out;
    _Float16* img  = (_Float16*)d_ws;   // 512 KB fragment-ordered W image

    w_split2<<<dim3(128), dim3(256), 0, stream>>>(W, img);
    router_mfma<<<dim3(NTOK / 32), dim3(256), 0, stream>>>(x, img, out);
}

// Round 5
// 206.053 us; speedup vs baseline: 1.0975x; 1.0975x over previous
//
#include <hip/hip_runtime.h>
#include <math.h>

// MoE router: logits = x[16384,2048] @ W^T[2048,64]; softmax; top-2; renorm.
//
// R10 post-mortem (85.6us, HBM 11%, Mfma 5.7%, VGPR=52): fragment-direct
// structure was right, but `#pragma unroll` on the K loop let LLVM sink every
// load to its use -> VGPR 52 proves the double-buffer never lived in regs ->
// zero prefetch distance, full 300-900cyc latency exposed 20x/wave at 2
// waves/SIMD. Latency-bound everywhere.
//
// R11 (resubmit; previous run died to a container infra failure, no result):
// same LDS-free structure, schedule carried by LOOP SHAPE:
//  (a) K loop is ROLLED (#pragma unroll 1), 2 steps/iter; the x prefetch for
//      step b+2/b+3 is consumed in the NEXT iteration -- a load crossing the
//      backedge cannot be sunk (no modulo sched on AMDGPU), so issue distance
//      >= 1 full iteration (~1000+cyc wall) > 900cyc HBM latency.
//  (b) W (L2-resident 512KB image) loaded per step as a 16-load batch right
//      before its CP; ~300cyc covered by TLP.
//  (c) occupancy 2->3 waves/SIMD: block = 4 waves = 16 tokens x 4 K-quarters
//      (512 k each), grid 1024, launch_bounds(256,3) = 12 waves/CU.
//      4-way fp32 reduction through a 17.4KB LDS slab at the end.
//
// fp16 split-precision MFMA (verified R5-R10, absmax <= 0.004): x=xh+xl,
// W=wh+wl, logits = xh*wh + xl*wh + xh*wl, fp32 acc.
// A-frags load DIRECTLY from global x (lane(c,q): row tok0+c, k = kq*512 +
// s*64 + ch*32 + 8q, row-contiguous 64B/lane/step).
// B-frags load DIRECTLY from the fragment-ordered pre-split W image:
// granule g = (((gs*2+ch)*4+nt)*2+h)*64 + L -> lane L holds hi/lo fp16 of
// W[nt*16+c][gs*64 + ch*32 + 8q .. +8]; 16B/lane perfectly coalesced.

typedef _Float16 half8  __attribute__((ext_vector_type(8)));
typedef float    floatx4 __attribute__((ext_vector_type(4)));

#define NTOK  16384
#define DDIM  2048
#define NE    64

__device__ inline void split8(const float4& a, const float4& b,
                              half8& hi, half8& lo) {
    float f[8] = {a.x, a.y, a.z, a.w, b.x, b.y, b.z, b.w};
#pragma unroll
    for (int j = 0; j < 8; ++j) {
        const _Float16 h = (_Float16)f[j];
        hi[j] = h;
        lo[j] = (_Float16)(f[j] - (float)h);
    }
}

// ---- kernel 1: pre-split W into fragment-ordered image (512 KB) ----
__global__ __launch_bounds__(256) void w_split2(const float* __restrict__ W,
                                                _Float16* __restrict__ img) {
    const int g  = blockIdx.x * 256 + threadIdx.x;  // granule idx 0..32767
    const int L  = g & 63;
    const int Bk = g >> 6;
    const int h  = Bk & 1;
    const int nt = (Bk >> 1) & 3;
    const int ch = (Bk >> 3) & 1;
    const int gs = Bk >> 4;          // global k64 step 0..31
    const int c  = L & 15, q = L >> 4;
    const float* src = W + (size_t)(nt * 16 + c) * DDIM
                         + gs * 64 + ch * 32 + q * 8;
    const float4 a = *(const float4*)(src);
    const float4 b = *(const float4*)(src + 4);
    half8 hi, lo;
    split8(a, b, hi, lo);
    *(half8*)(img + (size_t)g * 8) = h ? lo : hi;
}

// ---- kernel 2: rolled-loop fragment-direct GEMM + softmax + top-2 ----
__global__ __launch_bounds__(256, 3) void router_mfma(
    const float* __restrict__ x,
    const _Float16* __restrict__ img,
    float* __restrict__ out)
{
    __shared__ __align__(16) float lg[4 * 16 * 68];   // per-kq partial slabs

    const int tid = threadIdx.x;
    const int L   = tid & 63;
    const int kq  = __builtin_amdgcn_readfirstlane(tid >> 6);  // K quarter 0..3
    const int c   = L & 15, q = L >> 4;
    const int btok = blockIdx.x * 16;

    // per-lane bases: A row = token btok+c, k base = kq*512 + 8q
    const float*    xp = x + (size_t)(btok + c) * DDIM + kq * 512 + q * 8;
    const _Float16* wp = img + (size_t)kq * 65536 + (size_t)L * 8;

    floatx4 acc[4];
#pragma unroll
    for (int nt = 0; nt < 4; ++nt) acc[nt] = (floatx4)0.f;

    float4 xA[4], xB[4];   // [2*ch + half]: 64B/lane per k64 step

    auto LX = [&](int s, float4* xb) {
#pragma unroll
        for (int ch = 0; ch < 2; ++ch) {
            xb[2 * ch + 0] = *(const float4*)(xp + s * 64 + ch * 32);
            xb[2 * ch + 1] = *(const float4*)(xp + s * 64 + ch * 32 + 4);
        }
    };
    auto LW = [&](int s, half8* wb) {
#pragma unroll
        for (int f = 0; f < 16; ++f)          // f = ch*8 + nt*2 + h
            wb[f] = *(const half8*)(wp + (size_t)s * 8192 + f * 512);
    };
    auto CP = [&](const float4* xb, const half8* wb) {
#pragma unroll
        for (int ch = 0; ch < 2; ++ch) {
            half8 Ah, Al;
            split8(xb[2 * ch], xb[2 * ch + 1], Ah, Al);
#pragma unroll
            for (int nt = 0; nt < 4; ++nt) {
                const half8 Bh = wb[ch * 8 + nt * 2];
                const half8 Bl = wb[ch * 8 + nt * 2 + 1];
                acc[nt] = __builtin_amdgcn_mfma_f32_16x16x32_f16(Ah, Bh, acc[nt], 0, 0, 0);
                acc[nt] = __builtin_amdgcn_mfma_f32_16x16x32_f16(Al, Bh, acc[nt], 0, 0, 0);
                acc[nt] = __builtin_amdgcn_mfma_f32_16x16x32_f16(Ah, Bl, acc[nt], 0, 0, 0);
            }
        }
    };

    // ---- K loop: 8 steps of k64, x prefetch crosses the backedge ----
    LX(0, xA);
    LX(1, xB);
#pragma unroll 1
    for (int b = 0; b < 6; b += 2) {
        half8 wA[16], wB[16];
        LW(b, wA);
        CP(xA, wA);          // consumes xA loaded one iteration ago
        LX(b + 2, xA);       // live across backedge -> cannot sink
        LW(b + 1, wB);
        CP(xB, wB);
        LX(b + 3, xB);       // live across backedge -> cannot sink
    }
    {
        half8 wA[16], wB[16];
        LW(6, wA); CP(xA, wA);
        LW(7, wB); CP(xB, wB);
    }

    // ---- per-kq partial scatter (C/D: col=lane&15, row=(L>>4)*4+r) ----
    {
        float* slab = &lg[kq * 16 * 68];
#pragma unroll
        for (int nt = 0; nt < 4; ++nt)
#pragma unroll
            for (int r = 0; r < 4; ++r)
                slab[(q * 4 + r) * 68 + nt * 16 + c] = acc[nt][r];
    }
    __syncthreads();

    // ---- 4-way reduction into slab 0: 1024 entries, 4 per thread ----
#pragma unroll
    for (int i = 0; i < 4; ++i) {
        const int e = tid + 256 * i;          // 0..1023
        const int r = e >> 6, col = e & 63;
        const int o = r * 68 + col;
        lg[o] = (lg[o] + lg[1088 + o]) + (lg[2176 + o] + lg[3264 + o]);
    }
    __syncthreads();

    // ---- softmax + top-2: thread t < 16 owns token btok+t ----
    if (tid < 16) {
        const int token = btok + tid;
        float* row = &lg[tid * 68];
        float pr[NE];
#pragma unroll
        for (int e = 0; e < NE; ++e) pr[e] = row[e];

        float m = pr[0];
#pragma unroll
        for (int e = 1; e < NE; ++e) m = fmaxf(m, pr[e]);
        float s = 0.f;
#pragma unroll
        for (int e = 0; e < NE; ++e) { pr[e] = expf(pr[e] - m); s += pr[e]; }
        const float inv = 1.f / s;

        // lax.top_k tie-break = lowest index first -> strict '>' ascending scan
        float v1 = -1.f; int i1 = 0;
#pragma unroll
        for (int e = 0; e < NE; ++e) { if (pr[e] > v1) { v1 = pr[e]; i1 = e; } }
        float v2 = -1.f; int i2 = 0;
#pragma unroll
        for (int e = 0; e < NE; ++e) { if (e != i1 && pr[e] > v2) { v2 = pr[e]; i2 = e; } }

        const float ts = v1 + v2;
        float* out_tp = out;              // top_k_probs  [NTOK][2]
        float* out_ti = out + 2 * NTOK;   // top_k_indices[NTOK][2] (float values)
        *(float2*)(out_tp + token * 2) = make_float2(v1 / ts, v2 / ts);
        *(float2*)(out_ti + token * 2) = make_float2((float)i1, (float)i2);

#pragma unroll
        for (int e = 0; e < NE; ++e) row[e] = pr[e] * inv;
    }
    __syncthreads();

    // ---- cooperative coalesced probs write: 16 tok x 64 = 1024 floats ----
    {
        float* out_p = out + 4 * NTOK + (size_t)btok * NE;
        const int r = tid >> 4, c4 = tid & 15;      // 256 float4s
        const float4 v = *(const float4*)&lg[r * 68 + 4 * c4];
        *(float4*)(out_p + tid * 4) = v;
    }
}

extern "C" void kernel_launch(void* const* d_in, const int* in_sizes, int n_in,
                              void* d_out, int out_size, void* d_ws, size_t ws_size,
                              hipStream_t stream) {
    const float* x = (const float*)d_in[0];
    const float* W = (const float*)d_in[1];
    float* out     = (float*)d_out;
    _Float16* img  = (_Float16*)d_ws;   // 512 KB fragment-ordered W image

    w_split2<<<dim3(128), dim3(256), 0, stream>>>(W, img);
    router_mfma<<<dim3(NTOK / 16), dim3(256), 0, stream>>>(x, img, out);
}